// Round 3
// baseline (855.518 us; speedup 1.0000x reference)
//
#include <hip/hip_runtime.h>

#define HID 2048
#define NHEADS 32
#define NKV 8
#define HEADD 64
#define BATCH 2
#define SEQ 2048
#define MTOT (BATCH*SEQ)      // 4096
#define KVDIM (NKV*HEADD)     // 512
#define KB64 (HID/32)         // 64 k-blocks

typedef _Float16 hf;
typedef hf hf8 __attribute__((ext_vector_type(8)));
typedef hf hf4 __attribute__((ext_vector_type(4)));
typedef float f32x4 __attribute__((ext_vector_type(4)));
typedef int iv2 __attribute__((ext_vector_type(2)));
typedef int iv4 __attribute__((ext_vector_type(4)));

#define MFMA16(a,b,c) __builtin_amdgcn_mfma_f32_16x16x32_f16(a, b, c, 0, 0, 0)

// pack two f32 -> one VGPR of 2xfp16 (v_cvt_pkrtz_f16_f32, single inst)
static __device__ __forceinline__ int pk2(float a, float b) {
    return __builtin_bit_cast(int, __builtin_amdgcn_cvt_pkrtz(a, b));
}

// async global->LDS, 16B per lane. LDS dest = wave-uniform base + lane*16.
static __device__ __forceinline__ void gld16(const hf* g, hf* l) {
    __builtin_amdgcn_global_load_lds(
        (const __attribute__((address_space(1))) void*)g,
        (__attribute__((address_space(3))) void*)l, 16, 0, 0);
}

// raw s_barrier flanked by compile-time memory fences (no vmcnt drain).
static __device__ __forceinline__ void fence_barrier() {
    asm volatile("" ::: "memory");
    __builtin_amdgcn_s_barrier();
    asm volatile("" ::: "memory");
}

// Panel layout (halves): addr(m,k) = ((m>>4)*(K/32) + (k>>5))*512 + (m&15)*32 + (k&31)

// ---------------------------------------------------------------------------
// Fused split: all five fp32 tensors -> hi/lo fp16 (x256) panels, one launch.
// ---------------------------------------------------------------------------
__global__ __launch_bounds__(256)
void split_all(const float* __restrict__ x,  const float* __restrict__ Wq,
               const float* __restrict__ Wk, const float* __restrict__ Wv,
               const float* __restrict__ Wo,
               hf* __restrict__ xh,  hf* __restrict__ xl,
               hf* __restrict__ wqh, hf* __restrict__ wql,
               hf* __restrict__ wkh, hf* __restrict__ wkl,
               hf* __restrict__ wvh, hf* __restrict__ wvl,
               hf* __restrict__ woh, hf* __restrict__ wol)
{
    const int bid = blockIdx.x;
    const float* src; hf *hi, *lo; int base;
    if (bid < 8192)       { src = x;  hi = xh;  lo = xl;  base = bid; }
    else if (bid < 12288) { src = Wq; hi = wqh; lo = wql; base = bid - 8192; }
    else if (bid < 13312) { src = Wk; hi = wkh; lo = wkl; base = bid - 12288; }
    else if (bid < 14336) { src = Wv; hi = wvh; lo = wvl; base = bid - 13312; }
    else                  { src = Wo; hi = woh; lo = wol; base = bid - 14336; }

    const int idx = (base * 256 + threadIdx.x) * 4;
    const int m = idx >> 11, k = idx & 2047;
    float4 v = *(const float4*)(src + idx);
    float s0 = v.x * 256.f, s1 = v.y * 256.f, s2 = v.z * 256.f, s3 = v.w * 256.f;
    hf h0 = (hf)s0, h1 = (hf)s1, h2 = (hf)s2, h3 = (hf)s3;
    hf4 hv = {h0, h1, h2, h3};
    hf4 lv = {(hf)(s0 - (float)h0), (hf)(s1 - (float)h1),
              (hf)(s2 - (float)h2), (hf)(s3 - (float)h3)};
    const size_t d = (size_t)(m >> 4) * 32768 + (size_t)(k >> 5) * 512
                   + ((m & 15) << 5) + (k & 31);
    *(hf4*)(hi + d) = hv;
    *(hf4*)(lo + d) = lv;
}

// ---------------------------------------------------------------------------
// LDS-staged GEMM mainloop: global_load_lds(16B) double-buffer, counted
// vmcnt(8) so the next k-block's loads stay in flight across the barrier.
// Wave roles: wave w stages array w of {Ah,Al,Bh,Bl} (8 x 1KB tiles = 8 glds).
// LDS: [buf][arr][tile][512] = 64KB -> 2 blocks/CU.
// ---------------------------------------------------------------------------
#define STAGE(bufi, kb) do { \
    _Pragma("unroll") for (int t = 0; t < 8; ++t) \
        gld16(gsrc0 + (size_t)t * 32768 + (size_t)(kb) * 512, \
              &lds_t[bufi][wave][t][0]); \
} while (0)

#define MAINLOOP_LDS \
    f32x4 acc[4][4]; \
    _Pragma("unroll") for (int i = 0; i < 4; ++i) \
    _Pragma("unroll") for (int j = 0; j < 4; ++j) acc[i][j] = {0.f,0.f,0.f,0.f}; \
    const hf* gsrc0; \
    { const hf* gb; size_t go; \
      if (wave < 2) { gb = wave ? Al : Ah; go = (size_t)(bm >> 4) * 32768; } \
      else          { gb = (wave == 3) ? Bl : Bh; go = (size_t)(bn >> 4) * 32768; } \
      gsrc0 = gb + go + (size_t)lane * 8; } \
    const int at0 = wm >> 4, bt0 = wn >> 4; \
    const int lofs = fr * 32 + fq * 8; \
    STAGE(0, 0); \
    for (int kb = 0; kb < KB64; ++kb) { \
        const int cur = kb & 1; \
        if (kb + 1 < KB64) { \
            STAGE(cur ^ 1, kb + 1); \
            asm volatile("s_waitcnt vmcnt(8)" ::: "memory"); \
        } else { \
            asm volatile("s_waitcnt vmcnt(0)" ::: "memory"); \
        } \
        fence_barrier(); \
        hf8 Fah[4], Fal[4], Fbh[4], Fbl[4]; \
        _Pragma("unroll") for (int t = 0; t < 4; ++t) { \
            Fah[t] = *(const hf8*)&lds_t[cur][0][at0 + t][lofs]; \
            Fal[t] = *(const hf8*)&lds_t[cur][1][at0 + t][lofs]; \
            Fbh[t] = *(const hf8*)&lds_t[cur][2][bt0 + t][lofs]; \
            Fbl[t] = *(const hf8*)&lds_t[cur][3][bt0 + t][lofs]; \
        } \
        _Pragma("unroll") for (int i = 0; i < 4; ++i) \
        _Pragma("unroll") for (int j = 0; j < 4; ++j) { \
            acc[i][j] = MFMA16(Fah[i], Fbh[j], acc[i][j]); \
            acc[i][j] = MFMA16(Fah[i], Fbl[j], acc[i][j]); \
            acc[i][j] = MFMA16(Fal[i], Fbh[j], acc[i][j]); \
        } \
        asm volatile("s_waitcnt lgkmcnt(0)" ::: "memory"); \
        fence_barrier(); \
    }

// ---------------------------------------------------------------------------
// Fused Q/K/V projection, LDS-staged + XCD-chunked swizzle (12x8 chunks).
// ---------------------------------------------------------------------------
__global__ __launch_bounds__(256, 2)
void gemm_qkv(const hf* __restrict__ xh, const hf* __restrict__ xl,
              const hf* __restrict__ wqh, const hf* __restrict__ wql,
              const hf* __restrict__ wkh, const hf* __restrict__ wkl,
              const hf* __restrict__ wvh, const hf* __restrict__ wvl,
              hf* __restrict__ qh, hf* __restrict__ ql,
              hf* __restrict__ kh, hf* __restrict__ kl,
              hf* __restrict__ vT)
{
    const int tid = threadIdx.x;
    const int lane = tid & 63, wave = tid >> 6;
    const int fr = lane & 15, fq = lane >> 4;
    const int wm = (wave & 1) * 64, wn = (wave >> 1) * 64;

    // grid 24x32 = 768 = 8 XCD-chunks of 12x8 (bijective; nwg%8==0)
    const int lin = blockIdx.y * 24 + blockIdx.x;
    const int xcd = lin & 7, pos = lin >> 3;       // pos in 0..95
    const int bx = (xcd & 1) * 12 + pos % 12;
    const int by = (xcd >> 1) * 8 + pos / 12;
    const int bm = by * 128;

    const hf *Bh, *Bl;
    hf *Oh = nullptr, *Ol = nullptr;
    int bn, Nout, mode;
    if (bx < 16)      { Bh = wqh; Bl = wql; bn = bx * 128;        Nout = HID;   Oh = qh; Ol = ql; mode = 1; }
    else if (bx < 20) { Bh = wkh; Bl = wkl; bn = (bx - 16) * 128; Nout = KVDIM; Oh = kh; Ol = kl; mode = 1; }
    else              { Bh = wvh; Bl = wvl; bn = (bx - 20) * 128; Nout = KVDIM; mode = 2; }

    const hf* Ah = xh; const hf* Al = xl;
    __shared__ alignas(16) hf lds_t[2][4][8][512];
    MAINLOOP_LDS

    if (mode == 1) {
        const float scale = 32.f / 65536.f;
#pragma unroll
        for (int j = 0; j < 4; ++j) {
            const int col = bn + wn + j * 16 + fr;
#pragma unroll
            for (int i = 0; i < 4; ++i) {
                const int row0 = bm + wm + i * 16 + fq * 4;
#pragma unroll
                for (int r = 0; r < 4; ++r) {
                    const size_t idx = (size_t)(row0 + r) * Nout + col;
                    float v = acc[i][j][r] * scale;
                    hf h = (hf)v;
                    Oh[idx] = h;
                    Ol[idx] = (hf)(v - (float)h);
                }
            }
        }
    } else {
        const float scale = 1.f / 65536.f;
#pragma unroll
        for (int j = 0; j < 4; ++j) {
            const int col = bn + wn + j * 16 + fr;             // d index
#pragma unroll
            for (int i = 0; i < 4; ++i) {
                const int row0 = bm + wm + i * 16 + fq * 4;    // seq index
                hf4 pk = {(hf)(acc[i][j][0] * scale), (hf)(acc[i][j][1] * scale),
                          (hf)(acc[i][j][2] * scale), (hf)(acc[i][j][3] * scale)};
                *(hf4*)(vT + (size_t)col * MTOT + row0) = pk;
            }
        }
    }
}

// ---------------------------------------------------------------------------
// Output projection, LDS-staged + XCD-chunked swizzle (8x8 chunks).
// ---------------------------------------------------------------------------
__global__ __launch_bounds__(256, 2)
void gemm_out(const hf* __restrict__ Ah, const hf* __restrict__ Al,
              const hf* __restrict__ Bh, const hf* __restrict__ Bl,
              const float* __restrict__ bias, float* __restrict__ Cf)
{
    const int tid = threadIdx.x;
    const int lane = tid & 63, wave = tid >> 6;
    const int fr = lane & 15, fq = lane >> 4;
    const int wm = (wave & 1) * 64, wn = (wave >> 1) * 64;

    // grid 16x32 = 512 = 8 XCD-chunks of 8x8 (bijective)
    const int lin = blockIdx.y * 16 + blockIdx.x;
    const int xcd = lin & 7, pos = lin >> 3;       // pos in 0..63
    const int bx = (xcd & 1) * 8 + (pos & 7);
    const int by = (xcd >> 1) * 8 + (pos >> 3);
    const int bm = by * 128, bn = bx * 128;

    __shared__ alignas(16) hf lds_t[2][4][8][512];
    MAINLOOP_LDS

    const float scale = 1.f / 65536.f;
#pragma unroll
    for (int j = 0; j < 4; ++j) {
        const int col = bn + wn + j * 16 + fr;
        const float bv = bias[col];
#pragma unroll
        for (int i = 0; i < 4; ++i) {
            const int row0 = bm + wm + i * 16 + fq * 4;
#pragma unroll
            for (int r = 0; r < 4; ++r)
                Cf[(size_t)(row0 + r) * HID + col] = acc[i][j][r] * scale + bv;
        }
    }
}

// ---------------------------------------------------------------------------
// Attention, S^T orientation, LDS-free. 32 q-rows per wave (nt=2), grid
// SEQ/128 -> 1024 blocks = 4 blocks/CU = 4 waves/SIMD fully resident.
// Occupancy was the round-1 bottleneck (2 waves/SIMD, MfmaUtil 28% with
// ~40% pure stall). XCD remap: XCD c owns kv-head c for both batches
// (1.5 MB K/V working set, L2-resident).
// ---------------------------------------------------------------------------
__global__ __launch_bounds__(256, 4)
void attn_st(const hf* __restrict__ Qhg, const hf* __restrict__ Qlg,
             const hf* __restrict__ Khg, const hf* __restrict__ Klg,
             const hf* __restrict__ Vtg,
             hf* __restrict__ Ohg, hf* __restrict__ Olg)
{
    const int tid  = threadIdx.x;
    const int lane = tid & 63, wave = tid >> 6;
    const int fr = lane & 15, fq = lane >> 4;
    // remap: lin in 0..511; XCD c (= lin&7) gets contiguous nl in
    // [c*64, c*64+63] -> hd range c*4..c*4+3 = one kv group.
    const int lin = blockIdx.y * 16 + blockIdx.x;      // 0..511
    const int nl  = (lin & 7) * 64 + (lin >> 3);
    const int hd  = nl >> 4;                           // head
    const int qblk = nl & 15;                          // 128-row q block
    const int b = blockIdx.z;
    const int kvh = hd >> 2;
    const int qbase = qblk * 128 + wave * 32;
    // S_true = S_raw/8192; exp(S_true) = exp2(S_raw * log2(e)/8192)
    const float SS2 = 1.4426950408889634f / 8192.f;

    // persistent Q fragments (B-operand: n=q-row=fr, k=d=fq*8+u+32s)
    hf8 qfh[2][2], qfl[2][2];
#pragma unroll
    for (int nt = 0; nt < 2; ++nt) {
        const size_t rb = (size_t)(b * SEQ + qbase + nt * 16 + fr) * HID + hd * 64;
#pragma unroll
        for (int s = 0; s < 2; ++s) {
            qfh[nt][s] = *(const hf8*)(Qhg + rb + s * 32 + fq * 8);
            qfl[nt][s] = *(const hf8*)(Qlg + rb + s * 32 + fq * 8);
        }
    }

    f32x4 oacc[4][2];                 // O^T tiles [d-tile][q-tile]
#pragma unroll
    for (int i = 0; i < 4; ++i)
#pragma unroll
        for (int j = 0; j < 2; ++j) oacc[i][j] = {0.f, 0.f, 0.f, 0.f};
    float lsum[2] = {0.f, 0.f};

    const size_t kbase = (size_t)(b * SEQ) * KVDIM + kvh * 64;
    const size_t vbase = (size_t)(kvh * 64) * MTOT + (size_t)(b * SEQ);

    hf8 k0h[2][2], k0l[2][2], k1h[2][2], k1l[2][2];   // [mt][s]

#define LOADK(KH, KL, t0) do { \
    _Pragma("unroll") for (int mt = 0; mt < 2; ++mt) { \
        const size_t kr = kbase + (size_t)((t0) + mt * 16 + fr) * KVDIM; \
        _Pragma("unroll") for (int s = 0; s < 2; ++s) { \
            KH[mt][s] = *(const hf8*)(Khg + kr + s * 32 + fq * 8); \
            KL[mt][s] = *(const hf8*)(Klg + kr + s * 32 + fq * 8); \
        } } } while (0)

#define CHUNK_BODY(KH, KL, t0) do { \
    hf8 vfr[4]; \
    _Pragma("unroll") for (int dt = 0; dt < 4; ++dt) \
        vfr[dt] = *(const hf8*)(Vtg + vbase + (size_t)(dt * 16 + fr) * MTOT \
                                + (t0) + fq * 8); \
    f32x4 sacc[2][2]; \
    _Pragma("unroll") for (int mt = 0; mt < 2; ++mt) \
    _Pragma("unroll") for (int nt = 0; nt < 2; ++nt) sacc[mt][nt] = {0.f,0.f,0.f,0.f}; \
    _Pragma("unroll") for (int mt = 0; mt < 2; ++mt) \
    _Pragma("unroll") for (int nt = 0; nt < 2; ++nt) \
    _Pragma("unroll") for (int s = 0; s < 2; ++s) { \
        sacc[mt][nt] = MFMA16(KH[mt][s], qfh[nt][s], sacc[mt][nt]); \
        sacc[mt][nt] = MFMA16(KH[mt][s], qfl[nt][s], sacc[mt][nt]); \
        sacc[mt][nt] = MFMA16(KL[mt][s], qfh[nt][s], sacc[mt][nt]); \
    } \
    hf8 pb[2]; \
    _Pragma("unroll") for (int nt = 0; nt < 2; ++nt) { \
        float e0 = __builtin_amdgcn_exp2f(sacc[0][nt][0] * SS2); \
        float e1 = __builtin_amdgcn_exp2f(sacc[0][nt][1] * SS2); \
        float e2 = __builtin_amdgcn_exp2f(sacc[0][nt][2] * SS2); \
        float e3 = __builtin_amdgcn_exp2f(sacc[0][nt][3] * SS2); \
        float g0 = __builtin_amdgcn_exp2f(sacc[1][nt][0] * SS2); \
        float g1 = __builtin_amdgcn_exp2f(sacc[1][nt][1] * SS2); \
        float g2 = __builtin_amdgcn_exp2f(sacc[1][nt][2] * SS2); \
        float g3 = __builtin_amdgcn_exp2f(sacc[1][nt][3] * SS2); \
        lsum[nt] += ((e0 + e1) + (e2 + e3)) + ((g0 + g1) + (g2 + g3)); \
        int a0 = pk2(e0, e1), a1 = pk2(e2, e3); \
        int c0 = pk2(g0, g1), c1 = pk2(g2, g3); \
        iv2 u0 = __builtin_amdgcn_permlane32_swap(a0, c0, false, false); \
        iv2 v0 = __builtin_amdgcn_permlane16_swap(u0.x, u0.y, false, false); \
        iv2 u1 = __builtin_amdgcn_permlane32_swap(a1, c1, false, false); \
        iv2 v1 = __builtin_amdgcn_permlane16_swap(u1.x, u1.y, false, false); \
        iv4 bq = {v0.x, v1.x, v0.y, v1.y}; \
        pb[nt] = __builtin_bit_cast(hf8, bq); \
    } \
    _Pragma("unroll") for (int dt = 0; dt < 4; ++dt) \
    _Pragma("unroll") for (int qt = 0; qt < 2; ++qt) \
        oacc[dt][qt] = MFMA16(vfr[dt], pb[qt], oacc[dt][qt]); \
} while (0)

    LOADK(k0h, k0l, 0);
    for (int t0 = 0; t0 < SEQ; t0 += 64) {
        LOADK(k1h, k1l, t0 + 32);          // prefetch odd chunk
        CHUNK_BODY(k0h, k0l, t0);          // compute even chunk
        if (t0 + 64 < SEQ) LOADK(k0h, k0l, t0 + 64);   // prefetch next even
        CHUNK_BODY(k1h, k1l, t0 + 32);     // compute odd chunk
    }
#undef LOADK
#undef CHUNK_BODY

#pragma unroll
    for (int qt = 0; qt < 2; ++qt) {
        lsum[qt] += __shfl_xor(lsum[qt], 16, 64);
        lsum[qt] += __shfl_xor(lsum[qt], 32, 64);
    }

    // epilogue: attn = O/l, store split(256*attn) in A-PANEL layout.
#pragma unroll
    for (int qt = 0; qt < 2; ++qt) {
        const float inv = 256.f / lsum[qt];
        const int pq = ((b * SEQ + qbase) >> 4) + qt;
#pragma unroll
        for (int dt = 0; dt < 4; ++dt) {
            float o0 = oacc[dt][qt][0] * inv, o1 = oacc[dt][qt][1] * inv;
            float o2 = oacc[dt][qt][2] * inv, o3 = oacc[dt][qt][3] * inv;
            hf h0 = (hf)o0, h1 = (hf)o1, h2 = (hf)o2, h3 = (hf)o3;
            hf4 hv = {h0, h1, h2, h3};
            hf4 lv = {(hf)(o0 - (float)h0), (hf)(o1 - (float)h1),
                      (hf)(o2 - (float)h2), (hf)(o3 - (float)h3)};
            const int kb = hd * 2 + (dt >> 1);
            const size_t d = (size_t)pq * 32768 + (size_t)kb * 512
                           + fr * 32 + (dt & 1) * 16 + fq * 4;
            *(hf4*)(Ohg + d) = hv;
            *(hf4*)(Olg + d) = lv;
        }
    }
}

// ---------------------------------------------------------------------------
extern "C" void kernel_launch(void* const* d_in, const int* in_sizes, int n_in,
                              void* d_out, int out_size, void* d_ws, size_t ws_size,
                              hipStream_t stream)
{
    const float* x  = (const float*)d_in[0];
    const float* Wq = (const float*)d_in[1];
    const float* Wk = (const float*)d_in[2];
    const float* Wv = (const float*)d_in[3];
    const float* Wo = (const float*)d_in[4];
    const float* bo = (const float*)d_in[5];
    float* out = (float*)d_out;
    (void)in_sizes; (void)n_in; (void)out_size; (void)ws_size;

    // workspace (halves), 116 MB. xh/xl reused as attn-output panels.
    hf* p = (hf*)d_ws;
    hf* xh  = p; p += (size_t)MTOT * HID;
    hf* xl  = p; p += (size_t)MTOT * HID;
    hf* qh  = p; p += (size_t)MTOT * HID;
    hf* ql  = p; p += (size_t)MTOT * HID;
    hf* kh  = p; p += (size_t)MTOT * KVDIM;
    hf* kl  = p; p += (size_t)MTOT * KVDIM;
    hf* vT  = p; p += (size_t)MTOT * KVDIM;
    hf* wqh = p; p += (size_t)HID * HID;
    hf* wql = p; p += (size_t)HID * HID;
    hf* wkh = p; p += (size_t)KVDIM * HID;
    hf* wkl = p; p += (size_t)KVDIM * HID;
    hf* wvh = p; p += (size_t)KVDIM * HID;
    hf* wvl = p; p += (size_t)KVDIM * HID;
    hf* woh = p; p += (size_t)HID * HID;
    hf* wol = p; p += (size_t)HID * HID;

    split_all<<<18432, 256, 0, stream>>>(x, Wq, Wk, Wv, Wo,
        xh, xl, wqh, wql, wkh, wkl, wvh, wvl, woh, wol);

    gemm_qkv<<<dim3(24, MTOT / 128), 256, 0, stream>>>(
        xh, xl, wqh, wql, wkh, wkl, wvh, wvl, qh, ql, kh, kl, vT);

    attn_st<<<dim3(SEQ / 128, NHEADS, BATCH), 256, 0, stream>>>(
        qh, ql, kh, kl, vT, xh, xl);

    gemm_out<<<dim3(HID / 128, MTOT / 128), 256, 0, stream>>>(
        xh, xl, woh, wol, bo, out);
}

// Round 7
// 676.163 us; speedup vs baseline: 1.2653x; 1.2653x over previous
//
#include <hip/hip_runtime.h>

#define HID 2048
#define NHEADS 32
#define NKV 8
#define HEADD 64
#define BATCH 2
#define SEQ 2048
#define MTOT (BATCH*SEQ)      // 4096
#define KVDIM (NKV*HEADD)     // 512
#define KB64 (HID/32)         // 64 k-blocks

typedef _Float16 hf;
typedef hf hf8 __attribute__((ext_vector_type(8)));
typedef hf hf4 __attribute__((ext_vector_type(4)));
typedef float f32x4 __attribute__((ext_vector_type(4)));
typedef int iv2 __attribute__((ext_vector_type(2)));
typedef int iv4 __attribute__((ext_vector_type(4)));

#define MFMA16(a,b,c) __builtin_amdgcn_mfma_f32_16x16x32_f16(a, b, c, 0, 0, 0)

// pack two f32 -> one VGPR of 2xfp16 (v_cvt_pkrtz_f16_f32, single inst)
static __device__ __forceinline__ int pk2(float a, float b) {
    return __builtin_bit_cast(int, __builtin_amdgcn_cvt_pkrtz(a, b));
}

// async global->LDS, 16B per lane. LDS dest = wave-uniform base + lane*16.
static __device__ __forceinline__ void gld16(const hf* g, hf* l) {
    __builtin_amdgcn_global_load_lds(
        (const __attribute__((address_space(1))) void*)g,
        (__attribute__((address_space(3))) void*)l, 16, 0, 0);
}

// raw s_barrier flanked by compile-time memory fences (no vmcnt drain).
static __device__ __forceinline__ void fence_barrier() {
    asm volatile("" ::: "memory");
    __builtin_amdgcn_s_barrier();
    asm volatile("" ::: "memory");
}

// Panel layout (halves): addr(m,k) = ((m>>4)*(K/32) + (k>>5))*512 + (m&15)*32 + (k&31)

// ---------------------------------------------------------------------------
// Fused split: all five fp32 tensors -> hi/lo fp16 (x256) panels, one launch.
// ---------------------------------------------------------------------------
__global__ __launch_bounds__(256)
void split_all(const float* __restrict__ x,  const float* __restrict__ Wq,
               const float* __restrict__ Wk, const float* __restrict__ Wv,
               const float* __restrict__ Wo,
               hf* __restrict__ xh,  hf* __restrict__ xl,
               hf* __restrict__ wqh, hf* __restrict__ wql,
               hf* __restrict__ wkh, hf* __restrict__ wkl,
               hf* __restrict__ wvh, hf* __restrict__ wvl,
               hf* __restrict__ woh, hf* __restrict__ wol)
{
    const int bid = blockIdx.x;
    const float* src; hf *hi, *lo; int base;
    if (bid < 8192)       { src = x;  hi = xh;  lo = xl;  base = bid; }
    else if (bid < 12288) { src = Wq; hi = wqh; lo = wql; base = bid - 8192; }
    else if (bid < 13312) { src = Wk; hi = wkh; lo = wkl; base = bid - 12288; }
    else if (bid < 14336) { src = Wv; hi = wvh; lo = wvl; base = bid - 13312; }
    else                  { src = Wo; hi = woh; lo = wol; base = bid - 14336; }

    const int idx = (base * 256 + threadIdx.x) * 4;
    const int m = idx >> 11, k = idx & 2047;
    float4 v = *(const float4*)(src + idx);
    float s0 = v.x * 256.f, s1 = v.y * 256.f, s2 = v.z * 256.f, s3 = v.w * 256.f;
    hf h0 = (hf)s0, h1 = (hf)s1, h2 = (hf)s2, h3 = (hf)s3;
    hf4 hv = {h0, h1, h2, h3};
    hf4 lv = {(hf)(s0 - (float)h0), (hf)(s1 - (float)h1),
              (hf)(s2 - (float)h2), (hf)(s3 - (float)h3)};
    const size_t d = (size_t)(m >> 4) * 32768 + (size_t)(k >> 5) * 512
                   + ((m & 15) << 5) + (k & 31);
    *(hf4*)(hi + d) = hv;
    *(hf4*)(lo + d) = lv;
}

// ---------------------------------------------------------------------------
// LDS-staged GEMM mainloop: global_load_lds(16B) double-buffer, counted
// vmcnt(8) so the next k-block's loads stay in flight across the barrier.
// Wave roles: wave w stages array w of {Ah,Al,Bh,Bl} (8 x 1KB tiles = 8 glds).
// LDS: [buf][arr][tile][512] = 64KB -> 2 blocks/CU.
// ---------------------------------------------------------------------------
#define STAGE(bufi, kb) do { \
    _Pragma("unroll") for (int t = 0; t < 8; ++t) \
        gld16(gsrc0 + (size_t)t * 32768 + (size_t)(kb) * 512, \
              &lds_t[bufi][wave][t][0]); \
} while (0)

#define MAINLOOP_LDS \
    f32x4 acc[4][4]; \
    _Pragma("unroll") for (int i = 0; i < 4; ++i) \
    _Pragma("unroll") for (int j = 0; j < 4; ++j) acc[i][j] = {0.f,0.f,0.f,0.f}; \
    const hf* gsrc0; \
    { const hf* gb; size_t go; \
      if (wave < 2) { gb = wave ? Al : Ah; go = (size_t)(bm >> 4) * 32768; } \
      else          { gb = (wave == 3) ? Bl : Bh; go = (size_t)(bn >> 4) * 32768; } \
      gsrc0 = gb + go + (size_t)lane * 8; } \
    const int at0 = wm >> 4, bt0 = wn >> 4; \
    const int lofs = fr * 32 + fq * 8; \
    STAGE(0, 0); \
    for (int kb = 0; kb < KB64; ++kb) { \
        const int cur = kb & 1; \
        if (kb + 1 < KB64) { \
            STAGE(cur ^ 1, kb + 1); \
            asm volatile("s_waitcnt vmcnt(8)" ::: "memory"); \
        } else { \
            asm volatile("s_waitcnt vmcnt(0)" ::: "memory"); \
        } \
        fence_barrier(); \
        hf8 Fah[4], Fal[4], Fbh[4], Fbl[4]; \
        _Pragma("unroll") for (int t = 0; t < 4; ++t) { \
            Fah[t] = *(const hf8*)&lds_t[cur][0][at0 + t][lofs]; \
            Fal[t] = *(const hf8*)&lds_t[cur][1][at0 + t][lofs]; \
            Fbh[t] = *(const hf8*)&lds_t[cur][2][bt0 + t][lofs]; \
            Fbl[t] = *(const hf8*)&lds_t[cur][3][bt0 + t][lofs]; \
        } \
        _Pragma("unroll") for (int i = 0; i < 4; ++i) \
        _Pragma("unroll") for (int j = 0; j < 4; ++j) { \
            acc[i][j] = MFMA16(Fah[i], Fbh[j], acc[i][j]); \
            acc[i][j] = MFMA16(Fah[i], Fbl[j], acc[i][j]); \
            acc[i][j] = MFMA16(Fal[i], Fbh[j], acc[i][j]); \
        } \
        asm volatile("s_waitcnt lgkmcnt(0)" ::: "memory"); \
        fence_barrier(); \
    }

// ---------------------------------------------------------------------------
// Fused Q/K/V projection, LDS-staged + XCD-chunked swizzle (12x8 chunks).
// ---------------------------------------------------------------------------
__global__ __launch_bounds__(256, 2)
void gemm_qkv(const hf* __restrict__ xh, const hf* __restrict__ xl,
              const hf* __restrict__ wqh, const hf* __restrict__ wql,
              const hf* __restrict__ wkh, const hf* __restrict__ wkl,
              const hf* __restrict__ wvh, const hf* __restrict__ wvl,
              hf* __restrict__ qh, hf* __restrict__ ql,
              hf* __restrict__ kh, hf* __restrict__ kl,
              hf* __restrict__ vT)
{
    const int tid = threadIdx.x;
    const int lane = tid & 63, wave = tid >> 6;
    const int fr = lane & 15, fq = lane >> 4;
    const int wm = (wave & 1) * 64, wn = (wave >> 1) * 64;

    // grid 24x32 = 768 = 8 XCD-chunks of 12x8 (bijective; nwg%8==0)
    const int lin = blockIdx.y * 24 + blockIdx.x;
    const int xcd = lin & 7, pos = lin >> 3;       // pos in 0..95
    const int bx = (xcd & 1) * 12 + pos % 12;
    const int by = (xcd >> 1) * 8 + pos / 12;
    const int bm = by * 128;

    const hf *Bh, *Bl;
    hf *Oh = nullptr, *Ol = nullptr;
    int bn, Nout, mode;
    if (bx < 16)      { Bh = wqh; Bl = wql; bn = bx * 128;        Nout = HID;   Oh = qh; Ol = ql; mode = 1; }
    else if (bx < 20) { Bh = wkh; Bl = wkl; bn = (bx - 16) * 128; Nout = KVDIM; Oh = kh; Ol = kl; mode = 1; }
    else              { Bh = wvh; Bl = wvl; bn = (bx - 20) * 128; Nout = KVDIM; mode = 2; }

    const hf* Ah = xh; const hf* Al = xl;
    __shared__ alignas(16) hf lds_t[2][4][8][512];
    MAINLOOP_LDS

    if (mode == 1) {
        const float scale = 32.f / 65536.f;
#pragma unroll
        for (int j = 0; j < 4; ++j) {
            const int col = bn + wn + j * 16 + fr;
#pragma unroll
            for (int i = 0; i < 4; ++i) {
                const int row0 = bm + wm + i * 16 + fq * 4;
#pragma unroll
                for (int r = 0; r < 4; ++r) {
                    const size_t idx = (size_t)(row0 + r) * Nout + col;
                    float v = acc[i][j][r] * scale;
                    hf h = (hf)v;
                    Oh[idx] = h;
                    Ol[idx] = (hf)(v - (float)h);
                }
            }
        }
    } else {
        const float scale = 1.f / 65536.f;
#pragma unroll
        for (int j = 0; j < 4; ++j) {
            const int col = bn + wn + j * 16 + fr;             // d index
#pragma unroll
            for (int i = 0; i < 4; ++i) {
                const int row0 = bm + wm + i * 16 + fq * 4;    // seq index
                hf4 pk = {(hf)(acc[i][j][0] * scale), (hf)(acc[i][j][1] * scale),
                          (hf)(acc[i][j][2] * scale), (hf)(acc[i][j][3] * scale)};
                *(hf4*)(vT + (size_t)col * MTOT + row0) = pk;
            }
        }
    }
}

// ---------------------------------------------------------------------------
// Output projection, LDS-staged + XCD-chunked swizzle (8x8 chunks).
// ---------------------------------------------------------------------------
__global__ __launch_bounds__(256, 2)
void gemm_out(const hf* __restrict__ Ah, const hf* __restrict__ Al,
              const hf* __restrict__ Bh, const hf* __restrict__ Bl,
              const float* __restrict__ bias, float* __restrict__ Cf)
{
    const int tid = threadIdx.x;
    const int lane = tid & 63, wave = tid >> 6;
    const int fr = lane & 15, fq = lane >> 4;
    const int wm = (wave & 1) * 64, wn = (wave >> 1) * 64;

    // grid 16x32 = 512 = 8 XCD-chunks of 8x8 (bijective)
    const int lin = blockIdx.y * 16 + blockIdx.x;
    const int xcd = lin & 7, pos = lin >> 3;       // pos in 0..63
    const int bx = (xcd & 1) * 8 + (pos & 7);
    const int by = (xcd >> 1) * 8 + (pos >> 3);
    const int bm = by * 128, bn = bx * 128;

    __shared__ alignas(16) hf lds_t[2][4][8][512];
    MAINLOOP_LDS

    const float scale = 1.f / 65536.f;
#pragma unroll
    for (int j = 0; j < 4; ++j) {
        const int col = bn + wn + j * 16 + fr;
        const float bv = bias[col];
#pragma unroll
        for (int i = 0; i < 4; ++i) {
            const int row0 = bm + wm + i * 16 + fq * 4;
#pragma unroll
            for (int r = 0; r < 4; ++r)
                Cf[(size_t)(row0 + r) * HID + col] = acc[i][j][r] * scale + bv;
        }
    }
}

// ---------------------------------------------------------------------------
// Attention, S^T orientation, LDS-free. 32 q-rows per wave (nt=2), grid
// SEQ/128 -> 1024 blocks. Round-3 lesson: (256,4) cap of 128 regs forced
// massive scratch spill (WRITE_SIZE 1.08 GB). This round: SINGLE K buffer
// (-32 regs, per-wave state ~150) + __launch_bounds__(256,3) -> 3 waves/SIMD
// without spill. Exposed per-chunk K-load latency (~250cy L2) is hidden by
// the 3rd resident wave (no barriers in this kernel; waves desync freely).
// XCD remap: XCD c owns kv-head c for both batches (K/V L2-resident).
// ---------------------------------------------------------------------------
__global__ __launch_bounds__(256, 3)
void attn_st(const hf* __restrict__ Qhg, const hf* __restrict__ Qlg,
             const hf* __restrict__ Khg, const hf* __restrict__ Klg,
             const hf* __restrict__ Vtg,
             hf* __restrict__ Ohg, hf* __restrict__ Olg)
{
    const int tid  = threadIdx.x;
    const int lane = tid & 63, wave = tid >> 6;
    const int fr = lane & 15, fq = lane >> 4;
    // remap: lin in 0..511; XCD c (= lin&7) gets contiguous nl in
    // [c*64, c*64+63] -> hd range c*4..c*4+3 = one kv group.
    const int lin = blockIdx.y * 16 + blockIdx.x;      // 0..511
    const int nl  = (lin & 7) * 64 + (lin >> 3);
    const int hd  = nl >> 4;                           // head
    const int qblk = nl & 15;                          // 128-row q block
    const int b = blockIdx.z;
    const int kvh = hd >> 2;
    const int qbase = qblk * 128 + wave * 32;
    // S_true = S_raw/8192; exp(S_true) = exp2(S_raw * log2(e)/8192)
    const float SS2 = 1.4426950408889634f / 8192.f;

    // persistent Q fragments (B-operand: n=q-row=fr, k=d=fq*8+u+32s)
    hf8 qfh[2][2], qfl[2][2];
#pragma unroll
    for (int nt = 0; nt < 2; ++nt) {
        const size_t rb = (size_t)(b * SEQ + qbase + nt * 16 + fr) * HID + hd * 64;
#pragma unroll
        for (int s = 0; s < 2; ++s) {
            qfh[nt][s] = *(const hf8*)(Qhg + rb + s * 32 + fq * 8);
            qfl[nt][s] = *(const hf8*)(Qlg + rb + s * 32 + fq * 8);
        }
    }

    f32x4 oacc[4][2];                 // O^T tiles [d-tile][q-tile]
#pragma unroll
    for (int i = 0; i < 4; ++i)
#pragma unroll
        for (int j = 0; j < 2; ++j) oacc[i][j] = {0.f, 0.f, 0.f, 0.f};
    float lsum[2] = {0.f, 0.f};

    const size_t kbase = (size_t)(b * SEQ) * KVDIM + kvh * 64;
    const size_t vbase = (size_t)(kvh * 64) * MTOT + (size_t)(b * SEQ);

    hf8 kbh[2][2], kbl[2][2];   // single K buffer [mt][s]

#define LOADK(KH, KL, t0) do { \
    _Pragma("unroll") for (int mt = 0; mt < 2; ++mt) { \
        const size_t kr = kbase + (size_t)((t0) + mt * 16 + fr) * KVDIM; \
        _Pragma("unroll") for (int s = 0; s < 2; ++s) { \
            KH[mt][s] = *(const hf8*)(Khg + kr + s * 32 + fq * 8); \
            KL[mt][s] = *(const hf8*)(Klg + kr + s * 32 + fq * 8); \
        } } } while (0)

#define CHUNK_BODY(KH, KL, t0) do { \
    hf8 vfr[4]; \
    _Pragma("unroll") for (int dt = 0; dt < 4; ++dt) \
        vfr[dt] = *(const hf8*)(Vtg + vbase + (size_t)(dt * 16 + fr) * MTOT \
                                + (t0) + fq * 8); \
    f32x4 sacc[2][2]; \
    _Pragma("unroll") for (int mt = 0; mt < 2; ++mt) \
    _Pragma("unroll") for (int nt = 0; nt < 2; ++nt) sacc[mt][nt] = {0.f,0.f,0.f,0.f}; \
    _Pragma("unroll") for (int mt = 0; mt < 2; ++mt) \
    _Pragma("unroll") for (int nt = 0; nt < 2; ++nt) \
    _Pragma("unroll") for (int s = 0; s < 2; ++s) { \
        sacc[mt][nt] = MFMA16(KH[mt][s], qfh[nt][s], sacc[mt][nt]); \
        sacc[mt][nt] = MFMA16(KH[mt][s], qfl[nt][s], sacc[mt][nt]); \
        sacc[mt][nt] = MFMA16(KL[mt][s], qfh[nt][s], sacc[mt][nt]); \
    } \
    hf8 pb[2]; \
    _Pragma("unroll") for (int nt = 0; nt < 2; ++nt) { \
        float e0 = __builtin_amdgcn_exp2f(sacc[0][nt][0] * SS2); \
        float e1 = __builtin_amdgcn_exp2f(sacc[0][nt][1] * SS2); \
        float e2 = __builtin_amdgcn_exp2f(sacc[0][nt][2] * SS2); \
        float e3 = __builtin_amdgcn_exp2f(sacc[0][nt][3] * SS2); \
        float g0 = __builtin_amdgcn_exp2f(sacc[1][nt][0] * SS2); \
        float g1 = __builtin_amdgcn_exp2f(sacc[1][nt][1] * SS2); \
        float g2 = __builtin_amdgcn_exp2f(sacc[1][nt][2] * SS2); \
        float g3 = __builtin_amdgcn_exp2f(sacc[1][nt][3] * SS2); \
        lsum[nt] += ((e0 + e1) + (e2 + e3)) + ((g0 + g1) + (g2 + g3)); \
        int a0 = pk2(e0, e1), a1 = pk2(e2, e3); \
        int c0 = pk2(g0, g1), c1 = pk2(g2, g3); \
        iv2 u0 = __builtin_amdgcn_permlane32_swap(a0, c0, false, false); \
        iv2 v0 = __builtin_amdgcn_permlane16_swap(u0.x, u0.y, false, false); \
        iv2 u1 = __builtin_amdgcn_permlane32_swap(a1, c1, false, false); \
        iv2 v1 = __builtin_amdgcn_permlane16_swap(u1.x, u1.y, false, false); \
        iv4 bq = {v0.x, v1.x, v0.y, v1.y}; \
        pb[nt] = __builtin_bit_cast(hf8, bq); \
    } \
    _Pragma("unroll") for (int dt = 0; dt < 4; ++dt) \
    _Pragma("unroll") for (int qt = 0; qt < 2; ++qt) \
        oacc[dt][qt] = MFMA16(vfr[dt], pb[qt], oacc[dt][qt]); \
} while (0)

    for (int t0 = 0; t0 < SEQ; t0 += 32) {
        LOADK(kbh, kbl, t0);
        CHUNK_BODY(kbh, kbl, t0);
    }
#undef LOADK
#undef CHUNK_BODY

#pragma unroll
    for (int qt = 0; qt < 2; ++qt) {
        lsum[qt] += __shfl_xor(lsum[qt], 16, 64);
        lsum[qt] += __shfl_xor(lsum[qt], 32, 64);
    }

    // epilogue: attn = O/l, store split(256*attn) in A-PANEL layout.
#pragma unroll
    for (int qt = 0; qt < 2; ++qt) {
        const float inv = 256.f / lsum[qt];
        const int pq = ((b * SEQ + qbase) >> 4) + qt;
#pragma unroll
        for (int dt = 0; dt < 4; ++dt) {
            float o0 = oacc[dt][qt][0] * inv, o1 = oacc[dt][qt][1] * inv;
            float o2 = oacc[dt][qt][2] * inv, o3 = oacc[dt][qt][3] * inv;
            hf h0 = (hf)o0, h1 = (hf)o1, h2 = (hf)o2, h3 = (hf)o3;
            hf4 hv = {h0, h1, h2, h3};
            hf4 lv = {(hf)(o0 - (float)h0), (hf)(o1 - (float)h1),
                      (hf)(o2 - (float)h2), (hf)(o3 - (float)h3)};
            const int kb = hd * 2 + (dt >> 1);
            const size_t d = (size_t)pq * 32768 + (size_t)kb * 512
                           + fr * 32 + (dt & 1) * 16 + fq * 4;
            *(hf4*)(Ohg + d) = hv;
            *(hf4*)(Olg + d) = lv;
        }
    }
}

// ---------------------------------------------------------------------------
extern "C" void kernel_launch(void* const* d_in, const int* in_sizes, int n_in,
                              void* d_out, int out_size, void* d_ws, size_t ws_size,
                              hipStream_t stream)
{
    const float* x  = (const float*)d_in[0];
    const float* Wq = (const float*)d_in[1];
    const float* Wk = (const float*)d_in[2];
    const float* Wv = (const float*)d_in[3];
    const float* Wo = (const float*)d_in[4];
    const float* bo = (const float*)d_in[5];
    float* out = (float*)d_out;
    (void)in_sizes; (void)n_in; (void)out_size; (void)ws_size;

    // workspace (halves), 116 MB. xh/xl reused as attn-output panels.
    hf* p = (hf*)d_ws;
    hf* xh  = p; p += (size_t)MTOT * HID;
    hf* xl  = p; p += (size_t)MTOT * HID;
    hf* qh  = p; p += (size_t)MTOT * HID;
    hf* ql  = p; p += (size_t)MTOT * HID;
    hf* kh  = p; p += (size_t)MTOT * KVDIM;
    hf* kl  = p; p += (size_t)MTOT * KVDIM;
    hf* vT  = p; p += (size_t)MTOT * KVDIM;
    hf* wqh = p; p += (size_t)HID * HID;
    hf* wql = p; p += (size_t)HID * HID;
    hf* wkh = p; p += (size_t)KVDIM * HID;
    hf* wkl = p; p += (size_t)KVDIM * HID;
    hf* wvh = p; p += (size_t)KVDIM * HID;
    hf* wvl = p; p += (size_t)KVDIM * HID;
    hf* woh = p; p += (size_t)HID * HID;
    hf* wol = p; p += (size_t)HID * HID;

    split_all<<<18432, 256, 0, stream>>>(x, Wq, Wk, Wv, Wo,
        xh, xl, wqh, wql, wkh, wkl, wvh, wvl, woh, wol);

    gemm_qkv<<<dim3(24, MTOT / 128), 256, 0, stream>>>(
        xh, xl, wqh, wql, wkh, wkl, wvh, wvl, qh, ql, kh, kl, vT);

    attn_st<<<dim3(SEQ / 128, NHEADS, BATCH), 256, 0, stream>>>(
        qh, ql, kh, kl, vT, xh, xl);

    gemm_out<<<dim3(HID / 128, MTOT / 128), 256, 0, stream>>>(
        xh, xl, woh, wol, bo, out);
}

// Round 10
// 468.091 us; speedup vs baseline: 1.8277x; 1.4445x over previous
//
#include <hip/hip_runtime.h>

#define HID 2048
#define NHEADS 32
#define NKV 8
#define HEADD 64
#define BATCH 2
#define SEQ 2048
#define MTOT (BATCH*SEQ)      // 4096
#define KVDIM (NKV*HEADD)     // 512
#define KB64 (HID/32)         // 64 k-blocks

typedef _Float16 hf;
typedef hf hf8 __attribute__((ext_vector_type(8)));
typedef hf hf4 __attribute__((ext_vector_type(4)));
typedef float f32x4 __attribute__((ext_vector_type(4)));
typedef int iv2 __attribute__((ext_vector_type(2)));
typedef int iv4 __attribute__((ext_vector_type(4)));

#define MFMA16(a,b,c) __builtin_amdgcn_mfma_f32_16x16x32_f16(a, b, c, 0, 0, 0)

// pack two f32 -> one VGPR of 2xfp16 (v_cvt_pkrtz_f16_f32, single inst)
static __device__ __forceinline__ int pk2(float a, float b) {
    return __builtin_bit_cast(int, __builtin_amdgcn_cvt_pkrtz(a, b));
}

// async global->LDS, 16B per lane. LDS dest = wave-uniform base + lane*16.
static __device__ __forceinline__ void gld16(const hf* g, hf* l) {
    __builtin_amdgcn_global_load_lds(
        (const __attribute__((address_space(1))) void*)g,
        (__attribute__((address_space(3))) void*)l, 16, 0, 0);
}

// raw s_barrier flanked by compile-time memory fences (no vmcnt drain).
static __device__ __forceinline__ void fence_barrier() {
    asm volatile("" ::: "memory");
    __builtin_amdgcn_s_barrier();
    asm volatile("" ::: "memory");
}

// Panel layout (halves): addr(m,k) = ((m>>4)*(K/32) + (k>>5))*512 + (m&15)*32 + (k&31)

// ---------------------------------------------------------------------------
// Fused split: all five fp32 tensors -> hi/lo fp16 (x256) panels, one launch.
// ---------------------------------------------------------------------------
__global__ __launch_bounds__(256)
void split_all(const float* __restrict__ x,  const float* __restrict__ Wq,
               const float* __restrict__ Wk, const float* __restrict__ Wv,
               const float* __restrict__ Wo,
               hf* __restrict__ xh,  hf* __restrict__ xl,
               hf* __restrict__ wqh, hf* __restrict__ wql,
               hf* __restrict__ wkh, hf* __restrict__ wkl,
               hf* __restrict__ wvh, hf* __restrict__ wvl,
               hf* __restrict__ woh, hf* __restrict__ wol)
{
    const int bid = blockIdx.x;
    const float* src; hf *hi, *lo; int base;
    if (bid < 8192)       { src = x;  hi = xh;  lo = xl;  base = bid; }
    else if (bid < 12288) { src = Wq; hi = wqh; lo = wql; base = bid - 8192; }
    else if (bid < 13312) { src = Wk; hi = wkh; lo = wkl; base = bid - 12288; }
    else if (bid < 14336) { src = Wv; hi = wvh; lo = wvl; base = bid - 13312; }
    else                  { src = Wo; hi = woh; lo = wol; base = bid - 14336; }

    const int idx = (base * 256 + threadIdx.x) * 4;
    const int m = idx >> 11, k = idx & 2047;
    float4 v = *(const float4*)(src + idx);
    float s0 = v.x * 256.f, s1 = v.y * 256.f, s2 = v.z * 256.f, s3 = v.w * 256.f;
    hf h0 = (hf)s0, h1 = (hf)s1, h2 = (hf)s2, h3 = (hf)s3;
    hf4 hv = {h0, h1, h2, h3};
    hf4 lv = {(hf)(s0 - (float)h0), (hf)(s1 - (float)h1),
              (hf)(s2 - (float)h2), (hf)(s3 - (float)h3)};
    const size_t d = (size_t)(m >> 4) * 32768 + (size_t)(k >> 5) * 512
                   + ((m & 15) << 5) + (k & 31);
    *(hf4*)(hi + d) = hv;
    *(hf4*)(lo + d) = lv;
}

// ---------------------------------------------------------------------------
// LDS-staged GEMM mainloop (unchanged): global_load_lds(16B) double-buffer,
// counted vmcnt(8). LDS: [buf][arr][tile][512] = 64KB -> 2 blocks/CU.
// ---------------------------------------------------------------------------
#define STAGE(bufi, kb) do { \
    _Pragma("unroll") for (int t = 0; t < 8; ++t) \
        gld16(gsrc0 + (size_t)t * 32768 + (size_t)(kb) * 512, \
              &lds_t[bufi][wave][t][0]); \
} while (0)

#define MAINLOOP_LDS \
    f32x4 acc[4][4]; \
    _Pragma("unroll") for (int i = 0; i < 4; ++i) \
    _Pragma("unroll") for (int j = 0; j < 4; ++j) acc[i][j] = {0.f,0.f,0.f,0.f}; \
    const hf* gsrc0; \
    { const hf* gb; size_t go; \
      if (wave < 2) { gb = wave ? Al : Ah; go = (size_t)(bm >> 4) * 32768; } \
      else          { gb = (wave == 3) ? Bl : Bh; go = (size_t)(bn >> 4) * 32768; } \
      gsrc0 = gb + go + (size_t)lane * 8; } \
    const int at0 = wm >> 4, bt0 = wn >> 4; \
    const int lofs = fr * 32 + fq * 8; \
    STAGE(0, 0); \
    for (int kb = 0; kb < KB64; ++kb) { \
        const int cur = kb & 1; \
        if (kb + 1 < KB64) { \
            STAGE(cur ^ 1, kb + 1); \
            asm volatile("s_waitcnt vmcnt(8)" ::: "memory"); \
        } else { \
            asm volatile("s_waitcnt vmcnt(0)" ::: "memory"); \
        } \
        fence_barrier(); \
        hf8 Fah[4], Fal[4], Fbh[4], Fbl[4]; \
        _Pragma("unroll") for (int t = 0; t < 4; ++t) { \
            Fah[t] = *(const hf8*)&lds_t[cur][0][at0 + t][lofs]; \
            Fal[t] = *(const hf8*)&lds_t[cur][1][at0 + t][lofs]; \
            Fbh[t] = *(const hf8*)&lds_t[cur][2][bt0 + t][lofs]; \
            Fbl[t] = *(const hf8*)&lds_t[cur][3][bt0 + t][lofs]; \
        } \
        _Pragma("unroll") for (int i = 0; i < 4; ++i) \
        _Pragma("unroll") for (int j = 0; j < 4; ++j) { \
            acc[i][j] = MFMA16(Fah[i], Fbh[j], acc[i][j]); \
            acc[i][j] = MFMA16(Fah[i], Fbl[j], acc[i][j]); \
            acc[i][j] = MFMA16(Fal[i], Fbh[j], acc[i][j]); \
        } \
        asm volatile("s_waitcnt lgkmcnt(0)" ::: "memory"); \
        fence_barrier(); \
    }

// ---------------------------------------------------------------------------
// Fused Q/K/V projection, LDS-staged + XCD-chunked swizzle (12x8 chunks).
// ---------------------------------------------------------------------------
__global__ __launch_bounds__(256, 2)
void gemm_qkv(const hf* __restrict__ xh, const hf* __restrict__ xl,
              const hf* __restrict__ wqh, const hf* __restrict__ wql,
              const hf* __restrict__ wkh, const hf* __restrict__ wkl,
              const hf* __restrict__ wvh, const hf* __restrict__ wvl,
              hf* __restrict__ qh, hf* __restrict__ ql,
              hf* __restrict__ kh, hf* __restrict__ kl,
              hf* __restrict__ vT)
{
    const int tid = threadIdx.x;
    const int lane = tid & 63, wave = tid >> 6;
    const int fr = lane & 15, fq = lane >> 4;
    const int wm = (wave & 1) * 64, wn = (wave >> 1) * 64;

    // grid 24x32 = 768 = 8 XCD-chunks of 12x8 (bijective; nwg%8==0)
    const int lin = blockIdx.y * 24 + blockIdx.x;
    const int xcd = lin & 7, pos = lin >> 3;       // pos in 0..95
    const int bx = (xcd & 1) * 12 + pos % 12;
    const int by = (xcd >> 1) * 8 + pos / 12;
    const int bm = by * 128;

    const hf *Bh, *Bl;
    hf *Oh = nullptr, *Ol = nullptr;
    int bn, Nout, mode;
    if (bx < 16)      { Bh = wqh; Bl = wql; bn = bx * 128;        Nout = HID;   Oh = qh; Ol = ql; mode = 1; }
    else if (bx < 20) { Bh = wkh; Bl = wkl; bn = (bx - 16) * 128; Nout = KVDIM; Oh = kh; Ol = kl; mode = 1; }
    else              { Bh = wvh; Bl = wvl; bn = (bx - 20) * 128; Nout = KVDIM; mode = 2; }

    const hf* Ah = xh; const hf* Al = xl;
    __shared__ alignas(16) hf lds_t[2][4][8][512];
    MAINLOOP_LDS

    if (mode == 1) {
        const float scale = 32.f / 65536.f;
#pragma unroll
        for (int j = 0; j < 4; ++j) {
            const int col = bn + wn + j * 16 + fr;
#pragma unroll
            for (int i = 0; i < 4; ++i) {
                const int row0 = bm + wm + i * 16 + fq * 4;
#pragma unroll
                for (int r = 0; r < 4; ++r) {
                    const size_t idx = (size_t)(row0 + r) * Nout + col;
                    float v = acc[i][j][r] * scale;
                    hf h = (hf)v;
                    Oh[idx] = h;
                    Ol[idx] = (hf)(v - (float)h);
                }
            }
        }
    } else {
        const float scale = 1.f / 65536.f;
#pragma unroll
        for (int j = 0; j < 4; ++j) {
            const int col = bn + wn + j * 16 + fr;             // d index
#pragma unroll
            for (int i = 0; i < 4; ++i) {
                const int row0 = bm + wm + i * 16 + fq * 4;    // seq index
                hf4 pk = {(hf)(acc[i][j][0] * scale), (hf)(acc[i][j][1] * scale),
                          (hf)(acc[i][j][2] * scale), (hf)(acc[i][j][3] * scale)};
                *(hf4*)(vT + (size_t)col * MTOT + row0) = pk;
            }
        }
    }
}

// ---------------------------------------------------------------------------
// Output projection, LDS-staged + XCD-chunked swizzle (8x8 chunks).
// ---------------------------------------------------------------------------
__global__ __launch_bounds__(256, 2)
void gemm_out(const hf* __restrict__ Ah, const hf* __restrict__ Al,
              const hf* __restrict__ Bh, const hf* __restrict__ Bl,
              const float* __restrict__ bias, float* __restrict__ Cf)
{
    const int tid = threadIdx.x;
    const int lane = tid & 63, wave = tid >> 6;
    const int fr = lane & 15, fq = lane >> 4;
    const int wm = (wave & 1) * 64, wn = (wave >> 1) * 64;

    // grid 16x32 = 512 = 8 XCD-chunks of 8x8 (bijective)
    const int lin = blockIdx.y * 16 + blockIdx.x;
    const int xcd = lin & 7, pos = lin >> 3;       // pos in 0..63
    const int bx = (xcd & 1) * 8 + (pos & 7);
    const int by = (xcd >> 1) * 8 + (pos >> 3);
    const int bm = by * 128, bn = bx * 128;

    __shared__ alignas(16) hf lds_t[2][4][8][512];
    MAINLOOP_LDS

    const float scale = 1.f / 65536.f;
#pragma unroll
    for (int j = 0; j < 4; ++j) {
        const int col = bn + wn + j * 16 + fr;
        const float bv = bias[col];
#pragma unroll
        for (int i = 0; i < 4; ++i) {
            const int row0 = bm + wm + i * 16 + fq * 4;
#pragma unroll
            for (int r = 0; r < 4; ++r)
                Cf[(size_t)(row0 + r) * HID + col] = acc[i][j][r] * scale + bv;
        }
    }
}

// ---------------------------------------------------------------------------
// Attention, S^T orientation. R7 lesson: per-wave K/V streaming is the
// bottleneck (4x redundant L2 traffic + either reg-dbuf spill or serial
// loads; 4 waves/SIMD did NOT hide it, MfmaUtil 15%). This round: K/V
// staged in LDS ONCE PER BLOCK (shared by 4 waves), double-buffered,
// async gld_lds + counted vmcnt(3) + 2 barriers/chunk — the GEMM-proven
// skeleton. XOR-swizzled LDS (both-sides: pre-swizzled source, swizzled
// ds_read) keeps b128 reads at the 8-cycle floor. nt=4 / 512 blocks /
// (256,2) = R1's proven register regime. LDS 24KB/block.
// ---------------------------------------------------------------------------
__global__ __launch_bounds__(256, 2)
void attn_st(const hf* __restrict__ Qhg, const hf* __restrict__ Qlg,
             const hf* __restrict__ Khg, const hf* __restrict__ Klg,
             const hf* __restrict__ Vtg,
             hf* __restrict__ Ohg, hf* __restrict__ Olg)
{
    const int tid  = threadIdx.x;
    const int lane = tid & 63, wave = tid >> 6;
    const int fr = lane & 15, fq = lane >> 4;
    // remap: lin 0..255; XCD c (= lin&7) gets nl in [c*32, c*32+31] ->
    // hd range c*4..c*4+3 = one kv group (K/V slice 1.5MB, L2-resident).
    const int lin = blockIdx.y * 8 + blockIdx.x;
    const int nl  = (lin & 7) * 32 + (lin >> 3);
    const int hd  = nl >> 3;
    const int b = blockIdx.z;
    const int kvh = hd >> 2;
    const int qbase = (nl & 7) * 256 + wave * 64;
    // S_true = S_raw/8192; exp(S_true) = exp2(S_raw * log2(e)/8192)
    const float SS2 = 1.4426950408889634f / 8192.f;

    // LDS K/V chunk buffers (double): K 32x64 (128B rows), V^T 64x32 (64B rows)
    __shared__ alignas(16) hf ldsKh[2][32][64];
    __shared__ alignas(16) hf ldsKl[2][32][64];
    __shared__ alignas(16) hf ldsV [2][64][32];

    // persistent Q fragments (B-operand: n=q-row=fr, k=d=fq*8+u+32s)
    hf8 qfh[4][2], qfl[4][2];
#pragma unroll
    for (int nt = 0; nt < 4; ++nt) {
        const size_t rb = (size_t)(b * SEQ + qbase + nt * 16 + fr) * HID + hd * 64;
#pragma unroll
        for (int s = 0; s < 2; ++s) {
            qfh[nt][s] = *(const hf8*)(Qhg + rb + s * 32 + fq * 8);
            qfl[nt][s] = *(const hf8*)(Qlg + rb + s * 32 + fq * 8);
        }
    }

    f32x4 oacc[4][4];                 // O^T tiles [d-tile][q-tile]
#pragma unroll
    for (int i = 0; i < 4; ++i)
#pragma unroll
        for (int j = 0; j < 4; ++j) oacc[i][j] = {0.f, 0.f, 0.f, 0.f};
    float lsum[4] = {0.f, 0.f, 0.f, 0.f};

    // staging sources (per-lane, pre-swizzled so linear LDS dest = swizzled).
    // K: wave stages rows [wave*8, wave*8+8); lane: row+=(lane>>3),
    //    16B slot (lane&7) holds logical slot (lane&7)^(lane>>3).
    const size_t ksrc = (size_t)(b * SEQ + wave * 8 + (lane >> 3)) * KVDIM
                      + kvh * 64 + 8 * ((lane & 7) ^ (lane >> 3));
    // V: wave stages d-rows [wave*16, wave*16+16); lane: row+=(lane>>2),
    //    16B slot (lane&3) holds logical slot (lane&3)^((lane>>2)&3).
    const size_t vsrc = (size_t)(kvh * 64 + wave * 16 + (lane >> 2)) * MTOT
                      + (size_t)(b * SEQ) + 8 * ((lane & 3) ^ ((lane >> 2) & 3));

#define STAGEA(bufi, t0) do { \
    gld16(Khg + ksrc + (size_t)(t0) * KVDIM, &ldsKh[bufi][wave * 8][0]); \
    gld16(Klg + ksrc + (size_t)(t0) * KVDIM, &ldsKl[bufi][wave * 8][0]); \
    gld16(Vtg + vsrc + (t0),                 &ldsV [bufi][wave * 16][0]); \
} while (0)

#define CHUNKA(buf) do { \
    const hf* Kh0 = &ldsKh[buf][0][0]; \
    const hf* Kl0 = &ldsKl[buf][0][0]; \
    const hf* V0  = &ldsV [buf][0][0]; \
    hf8 kfh[2][2], kfl[2][2], vfr[4]; \
    _Pragma("unroll") for (int mt = 0; mt < 2; ++mt) \
    _Pragma("unroll") for (int s = 0; s < 2; ++s) { \
        const int ko = (mt * 16 + fr) * 64 + 8 * ((s * 4 + fq) ^ (fr & 7)); \
        kfh[mt][s] = *(const hf8*)(Kh0 + ko); \
        kfl[mt][s] = *(const hf8*)(Kl0 + ko); \
    } \
    _Pragma("unroll") for (int dt = 0; dt < 4; ++dt) \
        vfr[dt] = *(const hf8*)(V0 + (dt * 16 + fr) * 32 + 8 * (fq ^ (fr & 3))); \
    f32x4 sacc[2][4]; \
    _Pragma("unroll") for (int mt = 0; mt < 2; ++mt) \
    _Pragma("unroll") for (int nt = 0; nt < 4; ++nt) sacc[mt][nt] = {0.f,0.f,0.f,0.f}; \
    _Pragma("unroll") for (int mt = 0; mt < 2; ++mt) \
    _Pragma("unroll") for (int nt = 0; nt < 4; ++nt) \
    _Pragma("unroll") for (int s = 0; s < 2; ++s) { \
        sacc[mt][nt] = MFMA16(kfh[mt][s], qfh[nt][s], sacc[mt][nt]); \
        sacc[mt][nt] = MFMA16(kfh[mt][s], qfl[nt][s], sacc[mt][nt]); \
        sacc[mt][nt] = MFMA16(kfl[mt][s], qfh[nt][s], sacc[mt][nt]); \
    } \
    hf8 pb[4]; \
    _Pragma("unroll") for (int nt = 0; nt < 4; ++nt) { \
        float e0 = __builtin_amdgcn_exp2f(sacc[0][nt][0] * SS2); \
        float e1 = __builtin_amdgcn_exp2f(sacc[0][nt][1] * SS2); \
        float e2 = __builtin_amdgcn_exp2f(sacc[0][nt][2] * SS2); \
        float e3 = __builtin_amdgcn_exp2f(sacc[0][nt][3] * SS2); \
        float g0 = __builtin_amdgcn_exp2f(sacc[1][nt][0] * SS2); \
        float g1 = __builtin_amdgcn_exp2f(sacc[1][nt][1] * SS2); \
        float g2 = __builtin_amdgcn_exp2f(sacc[1][nt][2] * SS2); \
        float g3 = __builtin_amdgcn_exp2f(sacc[1][nt][3] * SS2); \
        lsum[nt] += ((e0 + e1) + (e2 + e3)) + ((g0 + g1) + (g2 + g3)); \
        int a0 = pk2(e0, e1), a1 = pk2(e2, e3); \
        int c0 = pk2(g0, g1), c1 = pk2(g2, g3); \
        iv2 u0 = __builtin_amdgcn_permlane32_swap(a0, c0, false, false); \
        iv2 v0 = __builtin_amdgcn_permlane16_swap(u0.x, u0.y, false, false); \
        iv2 u1 = __builtin_amdgcn_permlane32_swap(a1, c1, false, false); \
        iv2 v1 = __builtin_amdgcn_permlane16_swap(u1.x, u1.y, false, false); \
        iv4 bq = {v0.x, v1.x, v0.y, v1.y}; \
        pb[nt] = __builtin_bit_cast(hf8, bq); \
    } \
    _Pragma("unroll") for (int dt = 0; dt < 4; ++dt) \
    _Pragma("unroll") for (int qt = 0; qt < 4; ++qt) \
        oacc[dt][qt] = MFMA16(vfr[dt], pb[qt], oacc[dt][qt]); \
} while (0)

    STAGEA(0, 0);
    for (int t0 = 0; t0 < SEQ; t0 += 32) {
        const int cur = (t0 >> 5) & 1;
        if (t0 + 32 < SEQ) {
            STAGEA(cur ^ 1, t0 + 32);
            asm volatile("s_waitcnt vmcnt(3)" ::: "memory");  // my 3 prev loads done
        } else {
            asm volatile("s_waitcnt vmcnt(0)" ::: "memory");
        }
        fence_barrier();            // all waves' staging for buf `cur` complete
        CHUNKA(cur);
        asm volatile("s_waitcnt lgkmcnt(0)" ::: "memory");
        fence_barrier();            // all waves done reading before overwrite
    }
#undef STAGEA
#undef CHUNKA

#pragma unroll
    for (int qt = 0; qt < 4; ++qt) {
        lsum[qt] += __shfl_xor(lsum[qt], 16, 64);
        lsum[qt] += __shfl_xor(lsum[qt], 32, 64);
    }

    // epilogue: attn = O/l, store split(256*attn) in A-PANEL layout.
#pragma unroll
    for (int qt = 0; qt < 4; ++qt) {
        const float inv = 256.f / lsum[qt];
        const int pq = ((b * SEQ + qbase) >> 4) + qt;
#pragma unroll
        for (int dt = 0; dt < 4; ++dt) {
            float o0 = oacc[dt][qt][0] * inv, o1 = oacc[dt][qt][1] * inv;
            float o2 = oacc[dt][qt][2] * inv, o3 = oacc[dt][qt][3] * inv;
            hf h0 = (hf)o0, h1 = (hf)o1, h2 = (hf)o2, h3 = (hf)o3;
            hf4 hv = {h0, h1, h2, h3};
            hf4 lv = {(hf)(o0 - (float)h0), (hf)(o1 - (float)h1),
                      (hf)(o2 - (float)h2), (hf)(o3 - (float)h3)};
            const int kb = hd * 2 + (dt >> 1);
            const size_t d = (size_t)pq * 32768 + (size_t)kb * 512
                           + fr * 32 + (dt & 1) * 16 + fq * 4;
            *(hf4*)(Ohg + d) = hv;
            *(hf4*)(Olg + d) = lv;
        }
    }
}

// ---------------------------------------------------------------------------
extern "C" void kernel_launch(void* const* d_in, const int* in_sizes, int n_in,
                              void* d_out, int out_size, void* d_ws, size_t ws_size,
                              hipStream_t stream)
{
    const float* x  = (const float*)d_in[0];
    const float* Wq = (const float*)d_in[1];
    const float* Wk = (const float*)d_in[2];
    const float* Wv = (const float*)d_in[3];
    const float* Wo = (const float*)d_in[4];
    const float* bo = (const float*)d_in[5];
    float* out = (float*)d_out;
    (void)in_sizes; (void)n_in; (void)out_size; (void)ws_size;

    // workspace (halves), 116 MB. xh/xl reused as attn-output panels.
    hf* p = (hf*)d_ws;
    hf* xh  = p; p += (size_t)MTOT * HID;
    hf* xl  = p; p += (size_t)MTOT * HID;
    hf* qh  = p; p += (size_t)MTOT * HID;
    hf* ql  = p; p += (size_t)MTOT * HID;
    hf* kh  = p; p += (size_t)MTOT * KVDIM;
    hf* kl  = p; p += (size_t)MTOT * KVDIM;
    hf* vT  = p; p += (size_t)MTOT * KVDIM;
    hf* wqh = p; p += (size_t)HID * HID;
    hf* wql = p; p += (size_t)HID * HID;
    hf* wkh = p; p += (size_t)KVDIM * HID;
    hf* wkl = p; p += (size_t)KVDIM * HID;
    hf* wvh = p; p += (size_t)KVDIM * HID;
    hf* wvl = p; p += (size_t)KVDIM * HID;
    hf* woh = p; p += (size_t)HID * HID;
    hf* wol = p; p += (size_t)HID * HID;

    split_all<<<18432, 256, 0, stream>>>(x, Wq, Wk, Wv, Wo,
        xh, xl, wqh, wql, wkh, wkl, wvh, wvl, woh, wol);

    gemm_qkv<<<dim3(24, MTOT / 128), 256, 0, stream>>>(
        xh, xl, wqh, wql, wkh, wkl, wvh, wvl, qh, ql, kh, kl, vT);

    attn_st<<<dim3(SEQ / 256, NHEADS, BATCH), 256, 0, stream>>>(
        qh, ql, kh, kl, vT, xh, xl);

    gemm_out<<<dim3(HID / 128, MTOT / 128), 256, 0, stream>>>(
        xh, xl, woh, wol, bo, out);
}

// Round 11
// 462.685 us; speedup vs baseline: 1.8490x; 1.0117x over previous
//
#include <hip/hip_runtime.h>

#define HID 2048
#define NHEADS 32
#define NKV 8
#define HEADD 64
#define BATCH 2
#define SEQ 2048
#define MTOT (BATCH*SEQ)      // 4096
#define KVDIM (NKV*HEADD)     // 512
#define KB64 (HID/32)         // 64 k-blocks

typedef _Float16 hf;
typedef hf hf8 __attribute__((ext_vector_type(8)));
typedef hf hf4 __attribute__((ext_vector_type(4)));
typedef float f32x4 __attribute__((ext_vector_type(4)));
typedef int iv2 __attribute__((ext_vector_type(2)));
typedef int iv4 __attribute__((ext_vector_type(4)));

#define MFMA16(a,b,c) __builtin_amdgcn_mfma_f32_16x16x32_f16(a, b, c, 0, 0, 0)

// pack two f32 -> one VGPR of 2xfp16 (v_cvt_pkrtz_f16_f32, single inst)
static __device__ __forceinline__ int pk2(float a, float b) {
    return __builtin_bit_cast(int, __builtin_amdgcn_cvt_pkrtz(a, b));
}

// async global->LDS, 16B per lane. LDS dest = wave-uniform base + lane*16.
static __device__ __forceinline__ void gld16(const hf* g, hf* l) {
    __builtin_amdgcn_global_load_lds(
        (const __attribute__((address_space(1))) void*)g,
        (__attribute__((address_space(3))) void*)l, 16, 0, 0);
}

// raw s_barrier flanked by compile-time memory fences (no vmcnt drain).
static __device__ __forceinline__ void fence_barrier() {
    asm volatile("" ::: "memory");
    __builtin_amdgcn_s_barrier();
    asm volatile("" ::: "memory");
}

// Panel layout (halves): addr(m,k) = ((m>>4)*(K/32) + (k>>5))*512 + (m&15)*32 + (k&31)

// ---------------------------------------------------------------------------
// Fused split: all five fp32 tensors -> hi/lo fp16 (x256) panels, one launch.
// ---------------------------------------------------------------------------
__global__ __launch_bounds__(256)
void split_all(const float* __restrict__ x,  const float* __restrict__ Wq,
               const float* __restrict__ Wk, const float* __restrict__ Wv,
               const float* __restrict__ Wo,
               hf* __restrict__ xh,  hf* __restrict__ xl,
               hf* __restrict__ wqh, hf* __restrict__ wql,
               hf* __restrict__ wkh, hf* __restrict__ wkl,
               hf* __restrict__ wvh, hf* __restrict__ wvl,
               hf* __restrict__ woh, hf* __restrict__ wol)
{
    const int bid = blockIdx.x;
    const float* src; hf *hi, *lo; int base;
    if (bid < 8192)       { src = x;  hi = xh;  lo = xl;  base = bid; }
    else if (bid < 12288) { src = Wq; hi = wqh; lo = wql; base = bid - 8192; }
    else if (bid < 13312) { src = Wk; hi = wkh; lo = wkl; base = bid - 12288; }
    else if (bid < 14336) { src = Wv; hi = wvh; lo = wvl; base = bid - 13312; }
    else                  { src = Wo; hi = woh; lo = wol; base = bid - 14336; }

    const int idx = (base * 256 + threadIdx.x) * 4;
    const int m = idx >> 11, k = idx & 2047;
    float4 v = *(const float4*)(src + idx);
    float s0 = v.x * 256.f, s1 = v.y * 256.f, s2 = v.z * 256.f, s3 = v.w * 256.f;
    hf h0 = (hf)s0, h1 = (hf)s1, h2 = (hf)s2, h3 = (hf)s3;
    hf4 hv = {h0, h1, h2, h3};
    hf4 lv = {(hf)(s0 - (float)h0), (hf)(s1 - (float)h1),
              (hf)(s2 - (float)h2), (hf)(s3 - (float)h3)};
    const size_t d = (size_t)(m >> 4) * 32768 + (size_t)(k >> 5) * 512
                   + ((m & 15) << 5) + (k & 31);
    *(hf4*)(hi + d) = hv;
    *(hf4*)(lo + d) = lv;
}

// ---------------------------------------------------------------------------
// LDS-staged GEMM mainloop: global_load_lds(16B) double-buffer, counted
// vmcnt(8). NEW (R10): 16B-slot rotate-swizzle to kill the 8-way ds_read
// bank conflict (SQ_LDS_BANK_CONFLICT was 12.6M/dispatch = ~16% of time).
// Tile = 16 rows x 4 slots(16B). Physical slot p holds logical slot
// (p - (row>>1))&3; staging pre-applies the inverse on the GLOBAL source
// (linear LDS dest, rule both-sides-or-neither), fragment read uses
// p = (fq + (fr>>1))&3 -> each 16-lane phase covers all 8 bank-groups
// 2x = conflict-free. LDS: [buf][arr][tile][512] = 64KB -> 2 blocks/CU.
// ---------------------------------------------------------------------------
#define STAGE(bufi, kb) do { \
    _Pragma("unroll") for (int t = 0; t < 8; ++t) \
        gld16(gsrc0 + (size_t)t * 32768 + (size_t)(kb) * 512, \
              &lds_t[bufi][wave][t][0]); \
} while (0)

#define MAINLOOP_LDS \
    f32x4 acc[4][4]; \
    _Pragma("unroll") for (int i = 0; i < 4; ++i) \
    _Pragma("unroll") for (int j = 0; j < 4; ++j) acc[i][j] = {0.f,0.f,0.f,0.f}; \
    const hf* gsrc0; \
    { const hf* gb; size_t go; \
      if (wave < 2) { gb = wave ? Al : Ah; go = (size_t)(bm >> 4) * 32768; } \
      else          { gb = (wave == 3) ? Bl : Bh; go = (size_t)(bn >> 4) * 32768; } \
      const int sr = lane >> 2, ss = lane & 3; \
      gsrc0 = gb + go + (size_t)(sr * 32 + (((ss - (sr >> 1)) & 3) * 8)); } \
    const int at0 = wm >> 4, bt0 = wn >> 4; \
    const int lofs = fr * 32 + (((fq + (fr >> 1)) & 3) * 8); \
    STAGE(0, 0); \
    for (int kb = 0; kb < KB64; ++kb) { \
        const int cur = kb & 1; \
        if (kb + 1 < KB64) { \
            STAGE(cur ^ 1, kb + 1); \
            asm volatile("s_waitcnt vmcnt(8)" ::: "memory"); \
        } else { \
            asm volatile("s_waitcnt vmcnt(0)" ::: "memory"); \
        } \
        fence_barrier(); \
        hf8 Fah[4], Fal[4], Fbh[4], Fbl[4]; \
        _Pragma("unroll") for (int t = 0; t < 4; ++t) { \
            Fah[t] = *(const hf8*)&lds_t[cur][0][at0 + t][lofs]; \
            Fal[t] = *(const hf8*)&lds_t[cur][1][at0 + t][lofs]; \
            Fbh[t] = *(const hf8*)&lds_t[cur][2][bt0 + t][lofs]; \
            Fbl[t] = *(const hf8*)&lds_t[cur][3][bt0 + t][lofs]; \
        } \
        _Pragma("unroll") for (int i = 0; i < 4; ++i) \
        _Pragma("unroll") for (int j = 0; j < 4; ++j) { \
            acc[i][j] = MFMA16(Fah[i], Fbh[j], acc[i][j]); \
            acc[i][j] = MFMA16(Fah[i], Fbl[j], acc[i][j]); \
            acc[i][j] = MFMA16(Fal[i], Fbh[j], acc[i][j]); \
        } \
        asm volatile("s_waitcnt lgkmcnt(0)" ::: "memory"); \
        fence_barrier(); \
    }

// ---------------------------------------------------------------------------
// Fused Q/K/V projection, LDS-staged + XCD-chunked swizzle (12x8 chunks).
// ---------------------------------------------------------------------------
__global__ __launch_bounds__(256, 2)
void gemm_qkv(const hf* __restrict__ xh, const hf* __restrict__ xl,
              const hf* __restrict__ wqh, const hf* __restrict__ wql,
              const hf* __restrict__ wkh, const hf* __restrict__ wkl,
              const hf* __restrict__ wvh, const hf* __restrict__ wvl,
              hf* __restrict__ qh, hf* __restrict__ ql,
              hf* __restrict__ kh, hf* __restrict__ kl,
              hf* __restrict__ vT)
{
    const int tid = threadIdx.x;
    const int lane = tid & 63, wave = tid >> 6;
    const int fr = lane & 15, fq = lane >> 4;
    const int wm = (wave & 1) * 64, wn = (wave >> 1) * 64;

    // grid 24x32 = 768 = 8 XCD-chunks of 12x8 (bijective; nwg%8==0)
    const int lin = blockIdx.y * 24 + blockIdx.x;
    const int xcd = lin & 7, pos = lin >> 3;       // pos in 0..95
    const int bx = (xcd & 1) * 12 + pos % 12;
    const int by = (xcd >> 1) * 8 + pos / 12;
    const int bm = by * 128;

    const hf *Bh, *Bl;
    hf *Oh = nullptr, *Ol = nullptr;
    int bn, Nout, mode;
    if (bx < 16)      { Bh = wqh; Bl = wql; bn = bx * 128;        Nout = HID;   Oh = qh; Ol = ql; mode = 1; }
    else if (bx < 20) { Bh = wkh; Bl = wkl; bn = (bx - 16) * 128; Nout = KVDIM; Oh = kh; Ol = kl; mode = 1; }
    else              { Bh = wvh; Bl = wvl; bn = (bx - 20) * 128; Nout = KVDIM; mode = 2; }

    const hf* Ah = xh; const hf* Al = xl;
    __shared__ alignas(16) hf lds_t[2][4][8][512];
    MAINLOOP_LDS

    if (mode == 1) {
        const float scale = 32.f / 65536.f;
#pragma unroll
        for (int j = 0; j < 4; ++j) {
            const int col = bn + wn + j * 16 + fr;
#pragma unroll
            for (int i = 0; i < 4; ++i) {
                const int row0 = bm + wm + i * 16 + fq * 4;
#pragma unroll
                for (int r = 0; r < 4; ++r) {
                    const size_t idx = (size_t)(row0 + r) * Nout + col;
                    float v = acc[i][j][r] * scale;
                    hf h = (hf)v;
                    Oh[idx] = h;
                    Ol[idx] = (hf)(v - (float)h);
                }
            }
        }
    } else {
        const float scale = 1.f / 65536.f;
#pragma unroll
        for (int j = 0; j < 4; ++j) {
            const int col = bn + wn + j * 16 + fr;             // d index
#pragma unroll
            for (int i = 0; i < 4; ++i) {
                const int row0 = bm + wm + i * 16 + fq * 4;    // seq index
                hf4 pk = {(hf)(acc[i][j][0] * scale), (hf)(acc[i][j][1] * scale),
                          (hf)(acc[i][j][2] * scale), (hf)(acc[i][j][3] * scale)};
                *(hf4*)(vT + (size_t)col * MTOT + row0) = pk;
            }
        }
    }
}

// ---------------------------------------------------------------------------
// Output projection, LDS-staged + XCD-chunked swizzle (8x8 chunks).
// ---------------------------------------------------------------------------
__global__ __launch_bounds__(256, 2)
void gemm_out(const hf* __restrict__ Ah, const hf* __restrict__ Al,
              const hf* __restrict__ Bh, const hf* __restrict__ Bl,
              const float* __restrict__ bias, float* __restrict__ Cf)
{
    const int tid = threadIdx.x;
    const int lane = tid & 63, wave = tid >> 6;
    const int fr = lane & 15, fq = lane >> 4;
    const int wm = (wave & 1) * 64, wn = (wave >> 1) * 64;

    // grid 16x32 = 512 = 8 XCD-chunks of 8x8 (bijective)
    const int lin = blockIdx.y * 16 + blockIdx.x;
    const int xcd = lin & 7, pos = lin >> 3;       // pos in 0..63
    const int bx = (xcd & 1) * 8 + (pos & 7);
    const int by = (xcd >> 1) * 8 + (pos >> 3);
    const int bm = by * 128, bn = bx * 128;

    __shared__ alignas(16) hf lds_t[2][4][8][512];
    MAINLOOP_LDS

    const float scale = 1.f / 65536.f;
#pragma unroll
    for (int j = 0; j < 4; ++j) {
        const int col = bn + wn + j * 16 + fr;
        const float bv = bias[col];
#pragma unroll
        for (int i = 0; i < 4; ++i) {
            const int row0 = bm + wm + i * 16 + fq * 4;
#pragma unroll
            for (int r = 0; r < 4; ++r)
                Cf[(size_t)(row0 + r) * HID + col] = acc[i][j][r] * scale + bv;
        }
    }
}

// ---------------------------------------------------------------------------
// Attention, S^T orientation (unchanged from R10's measured win): K/V staged
// in LDS once per block, double-buffered, gld_lds + counted vmcnt(3),
// XOR-swizzled both-sides. nt=4 / 512 blocks / (256,2).
// ---------------------------------------------------------------------------
__global__ __launch_bounds__(256, 2)
void attn_st(const hf* __restrict__ Qhg, const hf* __restrict__ Qlg,
             const hf* __restrict__ Khg, const hf* __restrict__ Klg,
             const hf* __restrict__ Vtg,
             hf* __restrict__ Ohg, hf* __restrict__ Olg)
{
    const int tid  = threadIdx.x;
    const int lane = tid & 63, wave = tid >> 6;
    const int fr = lane & 15, fq = lane >> 4;
    // remap: lin 0..255; XCD c (= lin&7) gets nl in [c*32, c*32+31] ->
    // hd range c*4..c*4+3 = one kv group (K/V slice 1.5MB, L2-resident).
    const int lin = blockIdx.y * 8 + blockIdx.x;
    const int nl  = (lin & 7) * 32 + (lin >> 3);
    const int hd  = nl >> 3;
    const int b = blockIdx.z;
    const int kvh = hd >> 2;
    const int qbase = (nl & 7) * 256 + wave * 64;
    // S_true = S_raw/8192; exp(S_true) = exp2(S_raw * log2(e)/8192)
    const float SS2 = 1.4426950408889634f / 8192.f;

    // LDS K/V chunk buffers (double): K 32x64 (128B rows), V^T 64x32 (64B rows)
    __shared__ alignas(16) hf ldsKh[2][32][64];
    __shared__ alignas(16) hf ldsKl[2][32][64];
    __shared__ alignas(16) hf ldsV [2][64][32];

    // persistent Q fragments (B-operand: n=q-row=fr, k=d=fq*8+u+32s)
    hf8 qfh[4][2], qfl[4][2];
#pragma unroll
    for (int nt = 0; nt < 4; ++nt) {
        const size_t rb = (size_t)(b * SEQ + qbase + nt * 16 + fr) * HID + hd * 64;
#pragma unroll
        for (int s = 0; s < 2; ++s) {
            qfh[nt][s] = *(const hf8*)(Qhg + rb + s * 32 + fq * 8);
            qfl[nt][s] = *(const hf8*)(Qlg + rb + s * 32 + fq * 8);
        }
    }

    f32x4 oacc[4][4];                 // O^T tiles [d-tile][q-tile]
#pragma unroll
    for (int i = 0; i < 4; ++i)
#pragma unroll
        for (int j = 0; j < 4; ++j) oacc[i][j] = {0.f, 0.f, 0.f, 0.f};
    float lsum[4] = {0.f, 0.f, 0.f, 0.f};

    // staging sources (per-lane, pre-swizzled so linear LDS dest = swizzled).
    // K: wave stages rows [wave*8, wave*8+8); lane: row+=(lane>>3),
    //    16B slot (lane&7) holds logical slot (lane&7)^(lane>>3).
    const size_t ksrc = (size_t)(b * SEQ + wave * 8 + (lane >> 3)) * KVDIM
                      + kvh * 64 + 8 * ((lane & 7) ^ (lane >> 3));
    // V: wave stages d-rows [wave*16, wave*16+16); lane: row+=(lane>>2),
    //    16B slot (lane&3) holds logical slot (lane&3)^((lane>>2)&3).
    const size_t vsrc = (size_t)(kvh * 64 + wave * 16 + (lane >> 2)) * MTOT
                      + (size_t)(b * SEQ) + 8 * ((lane & 3) ^ ((lane >> 2) & 3));

#define STAGEA(bufi, t0) do { \
    gld16(Khg + ksrc + (size_t)(t0) * KVDIM, &ldsKh[bufi][wave * 8][0]); \
    gld16(Klg + ksrc + (size_t)(t0) * KVDIM, &ldsKl[bufi][wave * 8][0]); \
    gld16(Vtg + vsrc + (t0),                 &ldsV [bufi][wave * 16][0]); \
} while (0)

#define CHUNKA(buf) do { \
    const hf* Kh0 = &ldsKh[buf][0][0]; \
    const hf* Kl0 = &ldsKl[buf][0][0]; \
    const hf* V0  = &ldsV [buf][0][0]; \
    hf8 kfh[2][2], kfl[2][2], vfr[4]; \
    _Pragma("unroll") for (int mt = 0; mt < 2; ++mt) \
    _Pragma("unroll") for (int s = 0; s < 2; ++s) { \
        const int ko = (mt * 16 + fr) * 64 + 8 * ((s * 4 + fq) ^ (fr & 7)); \
        kfh[mt][s] = *(const hf8*)(Kh0 + ko); \
        kfl[mt][s] = *(const hf8*)(Kl0 + ko); \
    } \
    _Pragma("unroll") for (int dt = 0; dt < 4; ++dt) \
        vfr[dt] = *(const hf8*)(V0 + (dt * 16 + fr) * 32 + 8 * (fq ^ (fr & 3))); \
    f32x4 sacc[2][4]; \
    _Pragma("unroll") for (int mt = 0; mt < 2; ++mt) \
    _Pragma("unroll") for (int nt = 0; nt < 4; ++nt) sacc[mt][nt] = {0.f,0.f,0.f,0.f}; \
    _Pragma("unroll") for (int mt = 0; mt < 2; ++mt) \
    _Pragma("unroll") for (int nt = 0; nt < 4; ++nt) \
    _Pragma("unroll") for (int s = 0; s < 2; ++s) { \
        sacc[mt][nt] = MFMA16(kfh[mt][s], qfh[nt][s], sacc[mt][nt]); \
        sacc[mt][nt] = MFMA16(kfh[mt][s], qfl[nt][s], sacc[mt][nt]); \
        sacc[mt][nt] = MFMA16(kfl[mt][s], qfh[nt][s], sacc[mt][nt]); \
    } \
    hf8 pb[4]; \
    _Pragma("unroll") for (int nt = 0; nt < 4; ++nt) { \
        float e0 = __builtin_amdgcn_exp2f(sacc[0][nt][0] * SS2); \
        float e1 = __builtin_amdgcn_exp2f(sacc[0][nt][1] * SS2); \
        float e2 = __builtin_amdgcn_exp2f(sacc[0][nt][2] * SS2); \
        float e3 = __builtin_amdgcn_exp2f(sacc[0][nt][3] * SS2); \
        float g0 = __builtin_amdgcn_exp2f(sacc[1][nt][0] * SS2); \
        float g1 = __builtin_amdgcn_exp2f(sacc[1][nt][1] * SS2); \
        float g2 = __builtin_amdgcn_exp2f(sacc[1][nt][2] * SS2); \
        float g3 = __builtin_amdgcn_exp2f(sacc[1][nt][3] * SS2); \
        lsum[nt] += ((e0 + e1) + (e2 + e3)) + ((g0 + g1) + (g2 + g3)); \
        int a0 = pk2(e0, e1), a1 = pk2(e2, e3); \
        int c0 = pk2(g0, g1), c1 = pk2(g2, g3); \
        iv2 u0 = __builtin_amdgcn_permlane32_swap(a0, c0, false, false); \
        iv2 v0 = __builtin_amdgcn_permlane16_swap(u0.x, u0.y, false, false); \
        iv2 u1 = __builtin_amdgcn_permlane32_swap(a1, c1, false, false); \
        iv2 v1 = __builtin_amdgcn_permlane16_swap(u1.x, u1.y, false, false); \
        iv4 bq = {v0.x, v1.x, v0.y, v1.y}; \
        pb[nt] = __builtin_bit_cast(hf8, bq); \
    } \
    _Pragma("unroll") for (int dt = 0; dt < 4; ++dt) \
    _Pragma("unroll") for (int qt = 0; qt < 4; ++qt) \
        oacc[dt][qt] = MFMA16(vfr[dt], pb[qt], oacc[dt][qt]); \
} while (0)

    STAGEA(0, 0);
    for (int t0 = 0; t0 < SEQ; t0 += 32) {
        const int cur = (t0 >> 5) & 1;
        if (t0 + 32 < SEQ) {
            STAGEA(cur ^ 1, t0 + 32);
            asm volatile("s_waitcnt vmcnt(3)" ::: "memory");  // my 3 prev loads done
        } else {
            asm volatile("s_waitcnt vmcnt(0)" ::: "memory");
        }
        fence_barrier();            // all waves' staging for buf `cur` complete
        CHUNKA(cur);
        asm volatile("s_waitcnt lgkmcnt(0)" ::: "memory");
        fence_barrier();            // all waves done reading before overwrite
    }
#undef STAGEA
#undef CHUNKA

#pragma unroll
    for (int qt = 0; qt < 4; ++qt) {
        lsum[qt] += __shfl_xor(lsum[qt], 16, 64);
        lsum[qt] += __shfl_xor(lsum[qt], 32, 64);
    }

    // epilogue: attn = O/l, store split(256*attn) in A-PANEL layout.
#pragma unroll
    for (int qt = 0; qt < 4; ++qt) {
        const float inv = 256.f / lsum[qt];
        const int pq = ((b * SEQ + qbase) >> 4) + qt;
#pragma unroll
        for (int dt = 0; dt < 4; ++dt) {
            float o0 = oacc[dt][qt][0] * inv, o1 = oacc[dt][qt][1] * inv;
            float o2 = oacc[dt][qt][2] * inv, o3 = oacc[dt][qt][3] * inv;
            hf h0 = (hf)o0, h1 = (hf)o1, h2 = (hf)o2, h3 = (hf)o3;
            hf4 hv = {h0, h1, h2, h3};
            hf4 lv = {(hf)(o0 - (float)h0), (hf)(o1 - (float)h1),
                      (hf)(o2 - (float)h2), (hf)(o3 - (float)h3)};
            const int kb = hd * 2 + (dt >> 1);
            const size_t d = (size_t)pq * 32768 + (size_t)kb * 512
                           + fr * 32 + (dt & 1) * 16 + fq * 4;
            *(hf4*)(Ohg + d) = hv;
            *(hf4*)(Olg + d) = lv;
        }
    }
}

// ---------------------------------------------------------------------------
extern "C" void kernel_launch(void* const* d_in, const int* in_sizes, int n_in,
                              void* d_out, int out_size, void* d_ws, size_t ws_size,
                              hipStream_t stream)
{
    const float* x  = (const float*)d_in[0];
    const float* Wq = (const float*)d_in[1];
    const float* Wk = (const float*)d_in[2];
    const float* Wv = (const float*)d_in[3];
    const float* Wo = (const float*)d_in[4];
    const float* bo = (const float*)d_in[5];
    float* out = (float*)d_out;
    (void)in_sizes; (void)n_in; (void)out_size; (void)ws_size;

    // workspace (halves), 116 MB. xh/xl reused as attn-output panels.
    hf* p = (hf*)d_ws;
    hf* xh  = p; p += (size_t)MTOT * HID;
    hf* xl  = p; p += (size_t)MTOT * HID;
    hf* qh  = p; p += (size_t)MTOT * HID;
    hf* ql  = p; p += (size_t)MTOT * HID;
    hf* kh  = p; p += (size_t)MTOT * KVDIM;
    hf* kl  = p; p += (size_t)MTOT * KVDIM;
    hf* vT  = p; p += (size_t)MTOT * KVDIM;
    hf* wqh = p; p += (size_t)HID * HID;
    hf* wql = p; p += (size_t)HID * HID;
    hf* wkh = p; p += (size_t)KVDIM * HID;
    hf* wkl = p; p += (size_t)KVDIM * HID;
    hf* wvh = p; p += (size_t)KVDIM * HID;
    hf* wvl = p; p += (size_t)KVDIM * HID;
    hf* woh = p; p += (size_t)HID * HID;
    hf* wol = p; p += (size_t)HID * HID;

    split_all<<<18432, 256, 0, stream>>>(x, Wq, Wk, Wv, Wo,
        xh, xl, wqh, wql, wkh, wkl, wvh, wvl, woh, wol);

    gemm_qkv<<<dim3(24, MTOT / 128), 256, 0, stream>>>(
        xh, xl, wqh, wql, wkh, wkl, wvh, wvl, qh, ql, kh, kl, vT);

    attn_st<<<dim3(SEQ / 256, NHEADS, BATCH), 256, 0, stream>>>(
        qh, ql, kh, kl, vT, xh, xl);

    gemm_out<<<dim3(HID / 128, MTOT / 128), 256, 0, stream>>>(
        xh, xl, woh, wol, bo, out);
}